// Round 5
// baseline (81.306 us; speedup 1.0000x reference)
//
#include <hip/hip_runtime.h>
#include <math.h>

// ---------------- problem constants ----------------
#define HH 120
#define WW 160
#define NPTS (HH * WW)            // 19200
#define FXC 572.4114f
#define FYC 573.57043f
#define CXC 325.2611f
#define CYC 242.04899f

// chamfer tiling
#define CH_BT   192                // threads per block (3 waves)
#define CH_T    10                 // a-points per thread
#define CH_APB  (CH_BT * CH_T)     // 1920 a-points per block
#define CH_ABLK (NPTS / CH_APB)    // 10 a-blocks
#define CH_BTILE 192               // b-points per LDS tile (= blockDim, 1 staging round)
#define CH_SCH  (NPTS / CH_BTILE)  // 100 b-chunks
// grid = 10 * 100 * 2 = 2000 blocks x 3 waves = 6000 waves ~= 23.4 waves/CU,
// 7.8 workgroups/CU (under the per-CU workgroup cap that limited R4).

#define MASK_WGT 1.3989422804014327f   // exp(0)*inv_sqrt_2pi + 1

// finalize kernel geometry
#define GB_CH 64                   // blocks doing chamfer sum
#define GB_MK 16                   // blocks doing mask loss
#define GB_TOT (GB_CH + GB_MK)
#define CH_SEG (2 * NPTS / GB_CH)  // 600 elements per chamfer block
#define MK_SEG (NPTS / GB_MK)      // 1200 elements per mask block

__device__ __forceinline__ void backproject_pt(int idx, float d,
                                               float& px, float& py, float& pz) {
    int y = idx / WW;
    int x = idx - y * WW;
    px = ((float)x - CXC) * d * (1.0f / FXC);
    py = ((float)y - CYC) * d * (1.0f / FYC);
    pz = d;
}

__device__ __forceinline__ float min3f(float a, float b, float c) {
    float d;
    asm("v_min3_f32 %0, %1, %2, %3" : "=v"(d) : "v"(a), "v"(b), "v"(c));
    return d;
}

// ---------------- kernel 1: init mins to +inf, zero accumulators ----------------
__global__ void __launch_bounds__(256) init_k(int* __restrict__ mins,
                                              int* __restrict__ accs) {
    int i = blockIdx.x * 256 + threadIdx.x;
    if (i < 2 * NPTS) mins[i] = 0x7F800000;  // +inf bit pattern
    if (i < 6) accs[i] = 0;                  // accf[3] + acci[3]
}

// ---------------- kernel 2: chamfer partial mins ----------------
// grid: (CH_ABLK, CH_SCH, 2). blockIdx.z selects direction.
#define CH_BODY(Q0, Q1)                                                          \
    _Pragma("unroll")                                                            \
    for (int t = 0; t < CH_T; ++t) {                                             \
        float r0 = fmaf(nax[t], (Q0).x,                                          \
                        fmaf(nay[t], (Q0).y, fmaf(naz[t], (Q0).z, (Q0).w)));     \
        float r1 = fmaf(nax[t], (Q1).x,                                          \
                        fmaf(nay[t], (Q1).y, fmaf(naz[t], (Q1).z, (Q1).w)));     \
        mn[t] = min3f(mn[t], r0, r1);                                            \
    }

__global__ void __launch_bounds__(CH_BT, 8) chamfer_partial_k(
    const float* __restrict__ depth_src, const float* __restrict__ depth_tgt,
    int* __restrict__ mins_base) {
    const float* dA;
    const float* dB;
    int* mins;
    if (blockIdx.z == 0) { dA = depth_src; dB = depth_tgt; mins = mins_base; }
    else                 { dA = depth_tgt; dB = depth_src; mins = mins_base + NPTS; }

    __shared__ float4 bp[CH_BTILE];

    const int tid = threadIdx.x;
    const int ablk = blockIdx.x;
    const int s = blockIdx.y;

    // stage b tile: (2x, 2y, 2z, |b|^2) -- exactly one round (CH_BTILE == CH_BT)
    {
        int j = s * CH_BTILE + tid;
        float d = dB[j];
        float px, py, pz;
        backproject_pt(j, d, px, py, pz);
        bp[tid] = make_float4(2.0f * px, 2.0f * py, 2.0f * pz,
                              fmaf(px, px, fmaf(py, py, pz * pz)));
    }

    // load a points into registers (negated for the fma chain)
    float nax[CH_T], nay[CH_T], naz[CH_T], mn[CH_T];
#pragma unroll
    for (int t = 0; t < CH_T; ++t) {
        int i = ablk * CH_APB + t * CH_BT + tid;
        float d = dA[i];
        float px, py, pz;
        backproject_pt(i, d, px, py, pz);
        nax[t] = -px; nay[t] = -py; naz[t] = -pz;
        mn[t] = INFINITY;  // tracks min over j of (b2_j - 2*dot_j)
    }

    __syncthreads();

    // 3 fma per pair + 1 min3 per 2 pairs = 3.5 VALU ops/pair.
    // Software-pipelined: next (q0,q1) loaded before computing current,
    // so the lgkm wait sits behind ~70 VALU ops.
    float4 q0 = bp[0];
    float4 q1 = bp[1];
    for (int jj = 0; jj < CH_BTILE - 2; jj += 2) {
        float4 n0 = bp[jj + 2];
        float4 n1 = bp[jj + 3];
        CH_BODY(q0, q1)
        q0 = n0;
        q1 = n1;
    }
    CH_BODY(q0, q1)

    // finalize: d = max(a2 + (b2 - 2ab), 0); a2 recomputed here (3 fma).
    // max(.,0) commutes with min; values >= 0 so int ordering == float ordering.
#pragma unroll
    for (int t = 0; t < CH_T; ++t) {
        int i = ablk * CH_APB + t * CH_BT + tid;
        float a2 = fmaf(nax[t], nax[t], fmaf(nay[t], nay[t], naz[t] * naz[t]));
        float v = fmaxf(a2 + mn[t], 0.0f);
        atomicMin(&mins[i], __float_as_int(v));
    }
}

// ---------------- kernel 3: fused reduction + mask loss -> out[0], out[1] ----------------
// accf[0]=cham_sum, accf[1]=pos_sum, accf[2]=neg_sum
// acci[0]=pos_cnt,  acci[1]=neg_cnt,  acci[2]=done_counter
__global__ void __launch_bounds__(256) finalize_k(const int* __restrict__ mins,
                                                  const float* __restrict__ pm,
                                                  const float* __restrict__ ms,
                                                  float* __restrict__ accf,
                                                  int* __restrict__ acci,
                                                  float* __restrict__ out) {
    const int b = blockIdx.x;
    const int tid = threadIdx.x;
    __shared__ float ra[256], rb[256];
    __shared__ int ca[256], cb[256];

    if (b < GB_CH) {
        // chamfer partial sum over a 600-element segment
        float s = 0.0f;
        int base = b * CH_SEG;
        for (int i = tid; i < CH_SEG; i += 256) s += __int_as_float(mins[base + i]);
        ra[tid] = s;
        __syncthreads();
        for (int w = 128; w > 0; w >>= 1) {
            if (tid < w) ra[tid] += ra[tid + w];
            __syncthreads();
        }
        if (tid == 0) atomicAdd(&accf[0], ra[0]);
    } else {
        // mask loss partial over a 1200-element segment
        int base = (b - GB_CH) * MK_SEG;
        float ps = 0.0f, ns = 0.0f;
        int pc = 0, nc = 0;
        for (int i = tid; i < MK_SEG; i += 256) {
            float p = pm[base + i];
            p = fminf(fmaxf(p, 1e-7f), 1.0f - 1e-7f);
            float t = ms[base + i];
            if (t > 0.0f) {
                ps += -t * logf(p) * MASK_WGT;
                pc++;
            } else if (t == 0.0f) {
                ns += -logf(1.0f - p) * MASK_WGT;
                nc++;
            }
        }
        ra[tid] = ps; rb[tid] = ns; ca[tid] = pc; cb[tid] = nc;
        __syncthreads();
        for (int w = 128; w > 0; w >>= 1) {
            if (tid < w) {
                ra[tid] += ra[tid + w];
                rb[tid] += rb[tid + w];
                ca[tid] += ca[tid + w];
                cb[tid] += cb[tid + w];
            }
            __syncthreads();
        }
        if (tid == 0) {
            atomicAdd(&accf[1], ra[0]);
            atomicAdd(&accf[2], rb[0]);
            atomicAdd(&acci[0], ca[0]);
            atomicAdd(&acci[1], cb[0]);
        }
    }

    // last finished block computes the final outputs
    if (tid == 0) {
        __threadfence();
        int old = __hip_atomic_fetch_add(&acci[2], 1, __ATOMIC_ACQ_REL,
                                         __HIP_MEMORY_SCOPE_AGENT);
        if (old == GB_TOT - 1) {
            __threadfence();
            float cham = __hip_atomic_load(&accf[0], __ATOMIC_RELAXED, __HIP_MEMORY_SCOPE_AGENT);
            float pos  = __hip_atomic_load(&accf[1], __ATOMIC_RELAXED, __HIP_MEMORY_SCOPE_AGENT);
            float neg  = __hip_atomic_load(&accf[2], __ATOMIC_RELAXED, __HIP_MEMORY_SCOPE_AGENT);
            int cp = __hip_atomic_load(&acci[0], __ATOMIC_RELAXED, __HIP_MEMORY_SCOPE_AGENT);
            int cn = __hip_atomic_load(&acci[1], __ATOMIC_RELAXED, __HIP_MEMORY_SCOPE_AGENT);
            out[0] = cham * (1.0f / (float)NPTS);
            float loss = 0.0f;
            if (cp > 0) loss += pos / (float)cp;
            if (cn > 0) loss += neg / (float)cn;
            out[1] = loss;
        }
    }
}

// ---------------- launcher ----------------
extern "C" void kernel_launch(void* const* d_in, const int* in_sizes, int n_in,
                              void* d_out, int out_size, void* d_ws, size_t ws_size,
                              hipStream_t stream) {
    const float* pred_PM   = (const float*)d_in[0];
    const float* pred_Ms   = (const float*)d_in[1];
    const float* depth_src = (const float*)d_in[2];
    const float* depth_tgt = (const float*)d_in[3];
    float* out = (float*)d_out;

    int* mins = (int*)d_ws;                      // 2*NPTS ints
    float* accf = (float*)(mins + 2 * NPTS);     // 3 floats
    int* acci = (int*)(accf + 3);                // 3 ints

    init_k<<<(2 * NPTS + 255) / 256, 256, 0, stream>>>(mins, (int*)accf);
    chamfer_partial_k<<<dim3(CH_ABLK, CH_SCH, 2), CH_BT, 0, stream>>>(
        depth_src, depth_tgt, mins);
    finalize_k<<<GB_TOT, 256, 0, stream>>>(mins, pred_PM, pred_Ms, accf, acci, out);
}